// Round 5
// baseline (655.923 us; speedup 1.0000x reference)
//
#include <hip/hip_runtime.h>
#include <float.h>

// Problem constants
#define S_LEN 2048
#define BATCH 32
#define HCH   256
#define DCH   128
#define KCODES 512

typedef float  f32x4  __attribute__((ext_vector_type(4)));
typedef short  bf16x8 __attribute__((ext_vector_type(8)));
typedef short  short8 __attribute__((ext_vector_type(8)));

__device__ __forceinline__ float lrelu_f(float v) { return v >= 0.f ? v : 0.2f * v; }

// fp32 -> bf16 bits, round-to-nearest-even (finite values)
__device__ __forceinline__ short f2bf(float f) {
    unsigned u = __float_as_uint(f);
    u = u + 0x7fffu + ((u >> 16) & 1u);
    return (short)(u >> 16);
}
__device__ __forceinline__ float bf2f(unsigned short u) {
    return __uint_as_float(((unsigned)u) << 16);
}

// ---------------------------------------------------------------------------
// Codebook prep: cb[K][D] fp32 -> cb_hi/cb_lo bf16 [K][D], cnorm fp32
// ---------------------------------------------------------------------------
__global__ void prep_cb_split_kernel(const float* __restrict__ cb,
                                     short* __restrict__ cb_hi, short* __restrict__ cb_lo,
                                     float* __restrict__ cnorm) {
    int k = blockIdx.x * 256 + threadIdx.x;
    if (k < KCODES) {
        float s = 0.f;
        for (int d = 0; d < DCH; ++d) {
            float v = cb[k * DCH + d];
            s += v * v;
            short hi = f2bf(v);
            short lo = f2bf(v - bf2f((unsigned short)hi));
            cb_hi[k * DCH + d] = hi;
            cb_lo[k * DCH + d] = lo;
        }
        cnorm[k] = s;
    }
}

// ---------------------------------------------------------------------------
// Encoder weight prep: W[Cout][Cin][3] fp32 -> [3][Cout][Cin] bf16 hi/lo
// ---------------------------------------------------------------------------
__global__ void prep_w_split_kernel(const float* __restrict__ Wsrc,
                                    short* __restrict__ Wh, short* __restrict__ Wl,
                                    int Cout, int Cin) {
    int i = blockIdx.x * 256 + threadIdx.x;
    int total = 3 * Cout * Cin;
    if (i < total) {
        int t = i / (Cout * Cin);
        int rem = i - t * Cout * Cin;
        int co = rem / Cin;
        int ci = rem - co * Cin;
        float v = Wsrc[(co * Cin + ci) * 3 + t];
        short hi = f2bf(v);
        Wh[i] = hi;
        Wl[i] = f2bf(v - bf2f((unsigned short)hi));
    }
}

// ---------------------------------------------------------------------------
// Decoder weight prep: dw[Cout=256][Cin][3] fp32 -> wt[3][256][Cin] bf16
// ---------------------------------------------------------------------------
__global__ void prep_wdec_kernel(const float* __restrict__ Wsrc, short* __restrict__ Wdst,
                                 int Cin) {
    int i = blockIdx.x * 256 + threadIdx.x;
    int total = 3 * 256 * Cin;
    if (i < total) {
        int t = i / (256 * Cin);
        int rem = i - t * 256 * Cin;
        int co = rem / Cin;
        int ci = rem - co * Cin;
        Wdst[i] = f2bf(Wsrc[(co * Cin + ci) * 3 + t]);
    }
}

// ---------------------------------------------------------------------------
// Decoder conv3 weight repack: dw3[ci*3+t] fp32 -> w3t[t*256+ci] fp32
// ---------------------------------------------------------------------------
__global__ void prep_w3t_kernel(const float* __restrict__ w3, float* __restrict__ w3t) {
    int i = blockIdx.x * 256 + threadIdx.x;
    if (i < 768) {
        int t = i / 256, ci = i - t * 256;
        w3t[i] = w3[ci * 3 + t];
    }
}

// ---------------------------------------------------------------------------
// Encoder conv1 channels-last: x[B][S] -> h hi/lo bf16 [B][S][256], lrelu.
// ---------------------------------------------------------------------------
__global__ __launch_bounds__(256) void enc_conv1_cl_kernel(
        const float* __restrict__ x, short* __restrict__ h_hi, short* __restrict__ h_lo,
        const float* __restrict__ w, const float* __restrict__ bias) {
    __shared__ float ws[HCH * 3];
    __shared__ float bs[HCH];
    int tid = threadIdx.x;
    for (int i = tid; i < HCH * 3; i += 256) ws[i] = w[i];
    for (int i = tid; i < HCH; i += 256) bs[i] = bias[i];
    __syncthreads();
    int b = blockIdx.y;
    int s = blockIdx.x * 32 + (tid >> 3);
    int cch = tid & 7;
    const float* xb = x + (size_t)b * S_LEN;
    float xm = (s > 0) ? xb[s - 1] : 0.f;
    float x0 = xb[s];
    float xp = (s < S_LEN - 1) ? xb[s + 1] : 0.f;
    size_t base = ((size_t)(b * S_LEN + s)) * HCH + cch * 32;
#pragma unroll
    for (int cc = 0; cc < 4; ++cc) {
        short8 oh, ol;
#pragma unroll
        for (int e = 0; e < 8; ++e) {
            int co = cch * 32 + cc * 8 + e;
            float v = ws[co * 3 + 0] * xm + ws[co * 3 + 1] * x0 + ws[co * 3 + 2] * xp + bs[co];
            v = lrelu_f(v);
            short hi = f2bf(v);
            oh[e] = hi;
            ol[e] = f2bf(v - bf2f((unsigned short)hi));
        }
        *(short8*)(h_hi + base + cc * 8) = oh;
        *(short8*)(h_lo + base + cc * 8) = ol;
    }
}

// ---------------------------------------------------------------------------
// Encoder split-bf16 MFMA conv v2 (channels-last), k=3 SAME.
// K-chunk 64 (half the barriers), X stride 68 shorts (2-way bank alias =
// free), weights from global/L2, wave-private epilogue (1 barrier).
// LDS 35.4 KB -> 4 blocks/CU with __launch_bounds__(256,4).
// ---------------------------------------------------------------------------
__global__ __launch_bounds__(256, 4) void conv_mfma_split(
        const short* __restrict__ in_hi, const short* __restrict__ in_lo,
        short* __restrict__ out_hi, short* __restrict__ out_lo,
        const short* __restrict__ wt_hi, const short* __restrict__ wt_lo,
        const float* __restrict__ bias, int Cin, int Cout, int do_lrelu) {
    __shared__ short smem[17680];        // Xh[130][68] + Xl[130][68] = 35,360 B
    short* Xh = smem;
    short* Xl = smem + 130 * 68;

    const int tid = threadIdx.x;
    const int lane = tid & 63;
    const int w = tid >> 6;
    const int m = lane & 15;
    const int q = lane >> 4;
    const int sOff = (w & 1) * 64;
    const int cOff = (w >> 1) * 64;
    const int b = blockIdx.z;
    const int s0 = blockIdx.x * 128;
    const int co0 = blockIdx.y * 128;

    f32x4 acc[4][4];
    f32x4 zero4 = {0.f, 0.f, 0.f, 0.f};
#pragma unroll
    for (int i = 0; i < 4; ++i)
#pragma unroll
        for (int j = 0; j < 4; ++j) acc[i][j] = zero4;

    const short* inhb = in_hi + (size_t)b * S_LEN * Cin;
    const short* inlb = in_lo + (size_t)b * S_LEN * Cin;

    for (int ci0 = 0; ci0 < Cin; ci0 += 64) {
        __syncthreads();
        // X tile: rows s0-1 .. s0+128 (130) x 64 ci, hi+lo
        for (int c = tid; c < 2080; c += 256) {
            int r = c >> 4;
            int sub = c & 15;
            int half = sub >> 3;        // 0 = hi, 1 = lo
            int part = sub & 7;
            int s = s0 - 1 + r;
            float4 v = make_float4(0.f, 0.f, 0.f, 0.f);
            if (s >= 0 && s < S_LEN) {
                size_t goff = (size_t)s * Cin + ci0 + part * 8;
                v = half ? *(const float4*)(inlb + goff) : *(const float4*)(inhb + goff);
            }
            *(float4*)((half ? Xl : Xh) + r * 68 + part * 8) = v;
        }
        __syncthreads();

#pragma unroll
        for (int ks = 0; ks < 2; ++ks) {
            const int kofs = ks * 32;
#pragma unroll
            for (int t = 0; t < 3; ++t) {
                bf16x8 ah[4], al[4], bh[4], bl[4];
                // global (long-latency) loads first
#pragma unroll
                for (int j = 0; j < 4; ++j) {
                    size_t woff = ((size_t)(t * Cout + co0 + cOff + j * 16 + m)) * Cin + ci0 + kofs + q * 8;
                    bh[j] = *(const bf16x8*)(wt_hi + woff);
                    bl[j] = *(const bf16x8*)(wt_lo + woff);
                }
#pragma unroll
                for (int i = 0; i < 4; ++i) {
                    int row = sOff + i * 16 + m + t;
                    ah[i] = *(const bf16x8*)(Xh + row * 68 + kofs + q * 8);
                    al[i] = *(const bf16x8*)(Xl + row * 68 + kofs + q * 8);
                }
#pragma unroll
                for (int i = 0; i < 4; ++i)
#pragma unroll
                    for (int j = 0; j < 4; ++j) {
                        acc[i][j] = __builtin_amdgcn_mfma_f32_16x16x32_bf16(ah[i], bh[j], acc[i][j], 0, 0, 0);
                        acc[i][j] = __builtin_amdgcn_mfma_f32_16x16x32_bf16(ah[i], bl[j], acc[i][j], 0, 0, 0);
                        acc[i][j] = __builtin_amdgcn_mfma_f32_16x16x32_bf16(al[i], bh[j], acc[i][j], 0, 0, 0);
                    }
            }
        }
    }

    // Epilogue: one barrier, then wave-private LDS repack (no further syncs).
    __syncthreads();
    short* obH = smem + w * 2560;        // [64][20] hi
    short* obL = obH + 1280;             // [64][20] lo
#pragma unroll
    for (int j = 0; j < 4; ++j) {
        float bv = bias[co0 + cOff + j * 16 + m];
#pragma unroll
        for (int i = 0; i < 4; ++i) {
#pragma unroll
            for (int r = 0; r < 4; ++r) {
                float val = acc[i][j][r] + bv;
                if (do_lrelu) val = lrelu_f(val);
                short hi = f2bf(val);
                short lo = f2bf(val - bf2f((unsigned short)hi));
                int row = i * 16 + q * 4 + r;
                obH[row * 20 + m] = hi;
                obL[row * 20 + m] = lo;
            }
        }
        const int colchunk = lane & 1;
        const int rbase = lane >> 1;
#pragma unroll
        for (int it = 0; it < 2; ++it) {
            int row = it * 32 + rbase;
            short8 vh = *(const short8*)(obH + row * 20 + colchunk * 8);
            short8 vl = *(const short8*)(obL + row * 20 + colchunk * 8);
            size_t goff = ((size_t)(b * S_LEN + s0 + sOff + row)) * Cout
                        + co0 + cOff + j * 16 + colchunk * 8;
            *(short8*)(out_hi + goff) = vh;
            *(short8*)(out_lo + goff) = vl;
        }
    }
}

// ---------------------------------------------------------------------------
// VQ argmin via split-bf16 MFMA.  (unchanged)
// ---------------------------------------------------------------------------
__global__ __launch_bounds__(256) void vq_mfma_kernel(
        const short* __restrict__ z_hi, const short* __restrict__ z_lo,
        const short* __restrict__ cb_hi, const short* __restrict__ cb_lo,
        const float* __restrict__ cnorm, int* __restrict__ idx_out,
        float* __restrict__ idx_f_out) {
    __shared__ short smem[2 * 64 * 136];
    __shared__ float redv[64][4];
    __shared__ int   redi[64][4];
    short* Zh = smem;
    short* Zl = smem + 64 * 136;

    const int tid = threadIdx.x;
    const int lane = tid & 63;
    const int w = tid >> 6;
    const int m = lane & 15;
    const int q = lane >> 4;
    const int n0 = blockIdx.x * 64;

    for (int c = tid; c < 2048; c += 256) {
        int buf = c >> 10;
        int rem = c & 1023;
        int r = rem >> 4, part = rem & 15;
        size_t goff = (size_t)(n0 + r) * DCH + part * 8;
        float4 v = buf ? *(const float4*)(z_lo + goff) : *(const float4*)(z_hi + goff);
        *(float4*)((buf ? Zl : Zh) + r * 136 + part * 8) = v;
    }
    __syncthreads();

    float best[4][4];
    int besti[4][4];
#pragma unroll
    for (int i = 0; i < 4; ++i)
#pragma unroll
        for (int r = 0; r < 4; ++r) { best[i][r] = FLT_MAX; besti[i][r] = 0; }

    for (int k0 = 0; k0 < KCODES; k0 += 256) {
        f32x4 acc[4][4];
        f32x4 zero4 = {0.f, 0.f, 0.f, 0.f};
#pragma unroll
        for (int i = 0; i < 4; ++i)
#pragma unroll
            for (int j = 0; j < 4; ++j) acc[i][j] = zero4;

#pragma unroll
        for (int d0 = 0; d0 < DCH; d0 += 32) {
            bf16x8 ah[4], al[4], bh[4], bl[4];
#pragma unroll
            for (int j = 0; j < 4; ++j) {
                size_t coff = (size_t)(k0 + w * 64 + j * 16 + m) * DCH + d0 + q * 8;
                bh[j] = *(const bf16x8*)(cb_hi + coff);
                bl[j] = *(const bf16x8*)(cb_lo + coff);
            }
#pragma unroll
            for (int i = 0; i < 4; ++i) {
                int row = i * 16 + m;
                ah[i] = *(const bf16x8*)(Zh + row * 136 + d0 + q * 8);
                al[i] = *(const bf16x8*)(Zl + row * 136 + d0 + q * 8);
            }
#pragma unroll
            for (int i = 0; i < 4; ++i)
#pragma unroll
                for (int j = 0; j < 4; ++j) {
                    acc[i][j] = __builtin_amdgcn_mfma_f32_16x16x32_bf16(ah[i], bh[j], acc[i][j], 0, 0, 0);
                    acc[i][j] = __builtin_amdgcn_mfma_f32_16x16x32_bf16(ah[i], bl[j], acc[i][j], 0, 0, 0);
                    acc[i][j] = __builtin_amdgcn_mfma_f32_16x16x32_bf16(al[i], bh[j], acc[i][j], 0, 0, 0);
                }
        }
#pragma unroll
        for (int j = 0; j < 4; ++j) {
            int k = k0 + w * 64 + j * 16 + m;
            float cn = cnorm[k];
#pragma unroll
            for (int i = 0; i < 4; ++i)
#pragma unroll
                for (int r = 0; r < 4; ++r) {
                    float dv = cn - 2.f * acc[i][j][r];
                    if (dv < best[i][r]) { best[i][r] = dv; besti[i][r] = k; }
                }
        }
    }

#pragma unroll
    for (int mask = 1; mask < 16; mask <<= 1) {
#pragma unroll
        for (int i = 0; i < 4; ++i)
#pragma unroll
            for (int r = 0; r < 4; ++r) {
                float ov = __shfl_xor(best[i][r], mask);
                int oi = __shfl_xor(besti[i][r], mask);
                if (ov < best[i][r] || (ov == best[i][r] && oi < besti[i][r])) {
                    best[i][r] = ov; besti[i][r] = oi;
                }
            }
    }
    if (m == 0) {
#pragma unroll
        for (int i = 0; i < 4; ++i)
#pragma unroll
            for (int r = 0; r < 4; ++r) {
                int srow = i * 16 + q * 4 + r;
                redv[srow][w] = best[i][r];
                redi[srow][w] = besti[i][r];
            }
    }
    __syncthreads();
    if (tid < 64) {
        float bv = redv[tid][0];
        int bi = redi[tid][0];
#pragma unroll
        for (int w2 = 1; w2 < 4; ++w2) {
            float v = redv[tid][w2];
            int ii = redi[tid][w2];
            if (v < bv || (v == bv && ii < bi)) { bv = v; bi = ii; }
        }
        int n = n0 + tid;
        idx_out[n] = bi;
        idx_f_out[n] = (float)bi;
    }
}

// ---------------------------------------------------------------------------
// Fused gather + vq-sum: z_q bf16 [B][S][D] store + sum((z - cb[idx])^2).
// ---------------------------------------------------------------------------
__global__ __launch_bounds__(256) void gather_vqsum_kernel(
        const float* __restrict__ cb, const int* __restrict__ idxb,
        const short* __restrict__ z_hi, const short* __restrict__ z_lo,
        short* __restrict__ zq, float* __restrict__ acc_vq) {
    int tid = threadIdx.x;
    int b = blockIdx.y;
    int s = blockIdx.x * 32 + (tid >> 3);
    int dpart = tid & 7;
    int n = b * S_LEN + s;
    int k = idxb[n];
    const float* src = cb + (size_t)k * DCH + dpart * 16;
    size_t zoff = (size_t)n * DCH + dpart * 16;
    float sum = 0.f;
    short8 outv[2];
#pragma unroll
    for (int half = 0; half < 2; ++half) {
        float4 f0 = *(const float4*)(src + half * 8);
        float4 f1 = *(const float4*)(src + half * 8 + 4);
        bf16x8 zh = *(const bf16x8*)(z_hi + zoff + half * 8);
        bf16x8 zl = *(const bf16x8*)(z_lo + zoff + half * 8);
        float qv[8] = {f0.x, f0.y, f0.z, f0.w, f1.x, f1.y, f1.z, f1.w};
        short8 o;
#pragma unroll
        for (int e = 0; e < 8; ++e) {
            o[e] = f2bf(qv[e]);
            float zv = bf2f((unsigned short)zh[e]) + bf2f((unsigned short)zl[e]);
            float df = zv - qv[e];
            sum += df * df;
        }
        outv[half] = o;
    }
    *(short8*)(zq + zoff) = outv[0];
    *(short8*)(zq + zoff + 8) = outv[1];
    for (int off = 32; off > 0; off >>= 1) sum += __shfl_down(sum, off);
    __shared__ float wsum[4];
    if ((tid & 63) == 0) wsum[tid >> 6] = sum;
    __syncthreads();
    if (tid == 0) atomicAdd(acc_vq, wsum[0] + wsum[1] + wsum[2] + wsum[3]);
}

// ---------------------------------------------------------------------------
// Decoder bf16 MFMA conv v2 (channels-last): K-chunk 64, weights from
// global/L2 (no W LDS stage), X stride 68, wave-private epilogue.
// LDS 17.7 KB.  Cout fixed 256.
// ---------------------------------------------------------------------------
__global__ __launch_bounds__(256, 4) void conv_mfma_cl(
        const short* __restrict__ in, short* __restrict__ out,
        const short* __restrict__ wt, const float* __restrict__ bias,
        int Cin) {
    __shared__ short smem[8840];         // Xs[130][68] = 17,680 B
    short* Xs = smem;

    const int tid = threadIdx.x;
    const int lane = tid & 63;
    const int w = tid >> 6;
    const int m = lane & 15;
    const int q = lane >> 4;
    const int sOff = (w & 1) * 64;
    const int cOff = (w >> 1) * 64;
    const int b = blockIdx.z;
    const int s0 = blockIdx.x * 128;
    const int co0 = blockIdx.y * 128;

    f32x4 acc[4][4];
    f32x4 zero4 = {0.f, 0.f, 0.f, 0.f};
#pragma unroll
    for (int i = 0; i < 4; ++i)
#pragma unroll
        for (int j = 0; j < 4; ++j) acc[i][j] = zero4;

    const short* inb = in + (size_t)b * S_LEN * Cin;

    for (int ci0 = 0; ci0 < Cin; ci0 += 64) {
        __syncthreads();
        for (int c = tid; c < 1040; c += 256) {
            int r = c >> 3;
            int part = c & 7;
            int s = s0 - 1 + r;
            float4 v = make_float4(0.f, 0.f, 0.f, 0.f);
            if (s >= 0 && s < S_LEN)
                v = *(const float4*)(inb + (size_t)s * Cin + ci0 + part * 8);
            *(float4*)(Xs + r * 68 + part * 8) = v;
        }
        __syncthreads();

#pragma unroll
        for (int ks = 0; ks < 2; ++ks) {
            const int kofs = ks * 32;
#pragma unroll
            for (int t = 0; t < 3; ++t) {
                bf16x8 a[4], bb[4];
#pragma unroll
                for (int j = 0; j < 4; ++j)
                    bb[j] = *(const bf16x8*)(wt + ((size_t)(t * 256 + co0 + cOff + j * 16 + m)) * Cin + ci0 + kofs + q * 8);
#pragma unroll
                for (int i = 0; i < 4; ++i)
                    a[i] = *(const bf16x8*)(Xs + (sOff + i * 16 + m + t) * 68 + kofs + q * 8);
#pragma unroll
                for (int i = 0; i < 4; ++i)
#pragma unroll
                    for (int j = 0; j < 4; ++j)
                        acc[i][j] = __builtin_amdgcn_mfma_f32_16x16x32_bf16(
                            a[i], bb[j], acc[i][j], 0, 0, 0);
            }
        }
    }

    __syncthreads();
    short* ob = smem + w * 1280;         // [64][20], wave-private
#pragma unroll
    for (int j = 0; j < 4; ++j) {
        float bv = bias[co0 + cOff + j * 16 + m];
#pragma unroll
        for (int i = 0; i < 4; ++i) {
#pragma unroll
            for (int r = 0; r < 4; ++r) {
                float val = acc[i][j][r] + bv;
                val = lrelu_f(val);
                ob[(i * 16 + q * 4 + r) * 20 + m] = f2bf(val);
            }
        }
        const int colchunk = lane & 1;
        const int rbase = lane >> 1;
#pragma unroll
        for (int it = 0; it < 2; ++it) {
            int row = it * 32 + rbase;
            short8 v = *(const short8*)(ob + row * 20 + colchunk * 8);
            size_t goff = ((size_t)(b * S_LEN + s0 + sOff + row)) * 256
                        + co0 + cOff + j * 16 + colchunk * 8;
            *(short8*)(out + goff) = v;
        }
    }
}

// ---------------------------------------------------------------------------
// Decoder conv3, LDS-tiled (unchanged from round 4).
// ---------------------------------------------------------------------------
__global__ __launch_bounds__(256) void dec_conv3_tiled_kernel(
        const short* __restrict__ h, const float* __restrict__ w3t,
        const float* __restrict__ b3, const float* __restrict__ x,
        float* __restrict__ xr, float* __restrict__ acc_recon) {
    __shared__ short Zs[66 * 264];
    __shared__ float ws[3 * 256];
    __shared__ float wsum[4];
    int tid = threadIdx.x;
    int b = blockIdx.y;
    int s0 = blockIdx.x * 64;
    const short* hb = h + (size_t)b * S_LEN * HCH;
    for (int i = tid; i < 768; i += 256) ws[i] = w3t[i];
    for (int c = tid; c < 2112; c += 256) {
        int r = c >> 5, part = c & 31;
        int g = s0 - 1 + r;
        short8 v = {0, 0, 0, 0, 0, 0, 0, 0};
        if (g >= 0 && g < S_LEN)
            v = *(const short8*)(hb + (size_t)g * HCH + part * 8);
        *(short8*)(Zs + r * 264 + part * 8) = v;
    }
    __syncthreads();

    int quarter = tid & 3;
    int sl = tid >> 2;
    float a0 = 0.f, a1 = 0.f, a2 = 0.f, a3 = 0.f;
#pragma unroll
    for (int t = 0; t < 3; ++t) {
        const short* zrow = Zs + (sl + t) * 264 + quarter * 64;
        const float* wrow = ws + t * 256 + quarter * 64;
#pragma unroll
        for (int c = 0; c < 8; ++c) {
            bf16x8 v = *(const bf16x8*)(zrow + c * 8);
            float4 w0 = *(const float4*)(wrow + c * 8);
            float4 w1 = *(const float4*)(wrow + c * 8 + 4);
            a0 = fmaf(w0.x, bf2f((unsigned short)v[0]), a0);
            a1 = fmaf(w0.y, bf2f((unsigned short)v[1]), a1);
            a2 = fmaf(w0.z, bf2f((unsigned short)v[2]), a2);
            a3 = fmaf(w0.w, bf2f((unsigned short)v[3]), a3);
            a0 = fmaf(w1.x, bf2f((unsigned short)v[4]), a0);
            a1 = fmaf(w1.y, bf2f((unsigned short)v[5]), a1);
            a2 = fmaf(w1.z, bf2f((unsigned short)v[6]), a2);
            a3 = fmaf(w1.w, bf2f((unsigned short)v[7]), a3);
        }
    }
    float acc = (a0 + a1) + (a2 + a3);
    acc += __shfl_xor(acc, 1);
    acc += __shfl_xor(acc, 2);
    float df2 = 0.f;
    if (quarter == 0) {
        int s = s0 + sl;
        float tot = acc + b3[0];
        xr[b * S_LEN + s] = tot;
        float df = x[b * S_LEN + s] - tot;
        df2 = df * df;
    }
    for (int off = 32; off > 0; off >>= 1) df2 += __shfl_down(df2, off);
    int lane = tid & 63, wv = tid >> 6;
    if (lane == 0) wsum[wv] = df2;
    __syncthreads();
    if (tid == 0) atomicAdd(acc_recon, wsum[0] + wsum[1] + wsum[2] + wsum[3]);
}

// ---------------------------------------------------------------------------
__global__ void finalize_kernel(const float* __restrict__ accs, float* __restrict__ out) {
    if (threadIdx.x == 0) {
        float vqm = accs[0] / ((float)BATCH * S_LEN * DCH);
        float rm  = accs[1] / ((float)BATCH * S_LEN);
        float vq_loss = vqm * 0.05f;
        float commit  = vqm * 0.15f;
        float recon   = rm * 1.0f;
        out[0] = recon + vq_loss + commit;
        out[1] = recon;
        out[2] = vq_loss;
        out[3] = commit;
    }
}

// ---------------------------------------------------------------------------
extern "C" void kernel_launch(void* const* d_in, const int* in_sizes, int n_in,
                              void* d_out, int out_size, void* d_ws, size_t ws_size,
                              hipStream_t stream) {
    const float* x    = (const float*)d_in[0];
    const float* cb   = (const float*)d_in[1];
    const float* ew1  = (const float*)d_in[2];
    const float* eb1  = (const float*)d_in[3];
    const float* ew2  = (const float*)d_in[4];
    const float* eb2  = (const float*)d_in[5];
    const float* ew3  = (const float*)d_in[6];
    const float* eb3  = (const float*)d_in[7];
    const float* dw1  = (const float*)d_in[8];
    const float* db1  = (const float*)d_in[9];
    const float* dw2  = (const float*)d_in[10];
    const float* db2  = (const float*)d_in[11];
    const float* dw3  = (const float*)d_in[12];
    const float* db3  = (const float*)d_in[13];

    float* out = (float*)d_out;
    float* xr    = out;
    float* idx_f = out + BATCH * S_LEN;
    float* loss_out = out + 2 * BATCH * S_LEN;

    const size_t NH = (size_t)BATCH * S_LEN * HCH;   // 16,777,216
    const size_t ND = (size_t)BATCH * S_LEN * DCH;   // 8,388,608

    short* sp = (short*)d_ws;
    short* h1_hi = sp;
    short* h1_lo = sp + NH;
    short* z_hi  = sp;            // overlays h1 (dead after conv2)
    short* z_lo  = sp + ND;
    short* h1d_bf = sp;           // overlays z (dead after vq+gather_vqsum)
    short* h2_hi = sp + 2 * NH;
    short* h2_lo = sp + 3 * NH;
    short* zq_bf = sp + 2 * NH;   // overlays h2 (dead after conv3)
    short* h2d_bf = sp + 3 * NH;
    short* sm = sp + 4 * NH;
    short* cb_hi = sm; sm += KCODES * DCH;
    short* cb_lo = sm; sm += KCODES * DCH;
    short* w2_hi = sm; sm += 3 * HCH * HCH;
    short* w2_lo = sm; sm += 3 * HCH * HCH;
    short* w3_hi = sm; sm += 3 * DCH * HCH;
    short* w3_lo = sm; sm += 3 * DCH * HCH;
    short* wbf_d1 = sm; sm += 3 * 256 * DCH;
    short* wbf_d2 = sm; sm += 3 * 256 * HCH;
    float* cnorm = (float*)sm;
    int* idxb = (int*)(cnorm + KCODES);
    float* w3t = (float*)(idxb + BATCH * S_LEN);
    float* accs = w3t + 768;

    hipMemsetAsync(accs, 0, 2 * sizeof(float), stream);

    // prep
    prep_cb_split_kernel<<<2, 256, 0, stream>>>(cb, cb_hi, cb_lo, cnorm);
    prep_w_split_kernel<<<(3 * HCH * HCH + 255) / 256, 256, 0, stream>>>(ew2, w2_hi, w2_lo, HCH, HCH);
    prep_w_split_kernel<<<(3 * DCH * HCH + 255) / 256, 256, 0, stream>>>(ew3, w3_hi, w3_lo, DCH, HCH);
    prep_wdec_kernel<<<(3 * 256 * DCH + 255) / 256, 256, 0, stream>>>(dw1, wbf_d1, DCH);
    prep_wdec_kernel<<<(3 * 256 * HCH + 255) / 256, 256, 0, stream>>>(dw2, wbf_d2, HCH);
    prep_w3t_kernel<<<3, 256, 0, stream>>>(dw3, w3t);

    // encoder (split-bf16 MFMA)
    enc_conv1_cl_kernel<<<dim3(S_LEN / 32, BATCH), 256, 0, stream>>>(x, h1_hi, h1_lo, ew1, eb1);
    conv_mfma_split<<<dim3(S_LEN / 128, HCH / 128, BATCH), 256, 0, stream>>>(
        h1_hi, h1_lo, h2_hi, h2_lo, w2_hi, w2_lo, eb2, HCH, HCH, 1);
    conv_mfma_split<<<dim3(S_LEN / 128, DCH / 128, BATCH), 256, 0, stream>>>(
        h2_hi, h2_lo, z_hi, z_lo, w3_hi, w3_lo, eb3, HCH, DCH, 0);

    // VQ
    vq_mfma_kernel<<<(BATCH * S_LEN) / 64, 256, 0, stream>>>(
        z_hi, z_lo, cb_hi, cb_lo, cnorm, idxb, idx_f);
    gather_vqsum_kernel<<<dim3(S_LEN / 32, BATCH), 256, 0, stream>>>(
        cb, idxb, z_hi, z_lo, zq_bf, accs);

    // decoder (bf16 MFMA)
    conv_mfma_cl<<<dim3(S_LEN / 128, 2, BATCH), 256, 0, stream>>>(
        zq_bf, h1d_bf, wbf_d1, db1, DCH);
    conv_mfma_cl<<<dim3(S_LEN / 128, 2, BATCH), 256, 0, stream>>>(
        h1d_bf, h2d_bf, wbf_d2, db2, HCH);
    dec_conv3_tiled_kernel<<<dim3(S_LEN / 64, BATCH), 256, 0, stream>>>(
        h2d_bf, w3t, db3, x, xr, accs + 1);

    finalize_kernel<<<1, 64, 0, stream>>>(accs, loss_out);
}

// Round 6
// 569.212 us; speedup vs baseline: 1.1523x; 1.1523x over previous
//
#include <hip/hip_runtime.h>
#include <float.h>

// Problem constants
#define S_LEN 2048
#define BATCH 32
#define HCH   256
#define DCH   128
#define KCODES 512

typedef float  f32x4  __attribute__((ext_vector_type(4)));
typedef short  bf16x8 __attribute__((ext_vector_type(8)));
typedef short  short8 __attribute__((ext_vector_type(8)));

__device__ __forceinline__ float lrelu_f(float v) { return v >= 0.f ? v : 0.2f * v; }

// fp32 -> bf16 bits, round-to-nearest-even (finite values)
__device__ __forceinline__ short f2bf(float f) {
    unsigned u = __float_as_uint(f);
    u = u + 0x7fffu + ((u >> 16) & 1u);
    return (short)(u >> 16);
}
__device__ __forceinline__ float bf2f(unsigned short u) {
    return __uint_as_float(((unsigned)u) << 16);
}

// ---------------------------------------------------------------------------
// Codebook prep: cb[K][D] fp32 -> cb_hi/cb_lo bf16 [K][D], cnorm fp32
// ---------------------------------------------------------------------------
__global__ void prep_cb_split_kernel(const float* __restrict__ cb,
                                     short* __restrict__ cb_hi, short* __restrict__ cb_lo,
                                     float* __restrict__ cnorm) {
    int k = blockIdx.x * 256 + threadIdx.x;
    if (k < KCODES) {
        float s = 0.f;
        for (int d = 0; d < DCH; ++d) {
            float v = cb[k * DCH + d];
            s += v * v;
            short hi = f2bf(v);
            short lo = f2bf(v - bf2f((unsigned short)hi));
            cb_hi[k * DCH + d] = hi;
            cb_lo[k * DCH + d] = lo;
        }
        cnorm[k] = s;
    }
}

// ---------------------------------------------------------------------------
// Encoder weight prep: W[Cout][Cin][3] fp32 -> [3][Cout][Cin] bf16 hi/lo
// ---------------------------------------------------------------------------
__global__ void prep_w_split_kernel(const float* __restrict__ Wsrc,
                                    short* __restrict__ Wh, short* __restrict__ Wl,
                                    int Cout, int Cin) {
    int i = blockIdx.x * 256 + threadIdx.x;
    int total = 3 * Cout * Cin;
    if (i < total) {
        int t = i / (Cout * Cin);
        int rem = i - t * Cout * Cin;
        int co = rem / Cin;
        int ci = rem - co * Cin;
        float v = Wsrc[(co * Cin + ci) * 3 + t];
        short hi = f2bf(v);
        Wh[i] = hi;
        Wl[i] = f2bf(v - bf2f((unsigned short)hi));
    }
}

// ---------------------------------------------------------------------------
// Decoder weight prep: dw[Cout=256][Cin][3] fp32 -> wt[3][256][Cin] bf16
// ---------------------------------------------------------------------------
__global__ void prep_wdec_kernel(const float* __restrict__ Wsrc, short* __restrict__ Wdst,
                                 int Cin) {
    int i = blockIdx.x * 256 + threadIdx.x;
    int total = 3 * 256 * Cin;
    if (i < total) {
        int t = i / (256 * Cin);
        int rem = i - t * 256 * Cin;
        int co = rem / Cin;
        int ci = rem - co * Cin;
        Wdst[i] = f2bf(Wsrc[(co * Cin + ci) * 3 + t]);
    }
}

// ---------------------------------------------------------------------------
// Decoder conv3 weight repack: dw3[ci*3+t] fp32 -> w3t[t*256+ci] fp32
// ---------------------------------------------------------------------------
__global__ void prep_w3t_kernel(const float* __restrict__ w3, float* __restrict__ w3t) {
    int i = blockIdx.x * 256 + threadIdx.x;
    if (i < 768) {
        int t = i / 256, ci = i - t * 256;
        w3t[i] = w3[ci * 3 + t];
    }
}

// ---------------------------------------------------------------------------
// Encoder conv1 channels-last: x[B][S] -> h hi/lo bf16 [B][S][256], lrelu.
// ---------------------------------------------------------------------------
__global__ __launch_bounds__(256) void enc_conv1_cl_kernel(
        const float* __restrict__ x, short* __restrict__ h_hi, short* __restrict__ h_lo,
        const float* __restrict__ w, const float* __restrict__ bias) {
    __shared__ float ws[HCH * 3];
    __shared__ float bs[HCH];
    int tid = threadIdx.x;
    for (int i = tid; i < HCH * 3; i += 256) ws[i] = w[i];
    for (int i = tid; i < HCH; i += 256) bs[i] = bias[i];
    __syncthreads();
    int b = blockIdx.y;
    int s = blockIdx.x * 32 + (tid >> 3);
    int cch = tid & 7;
    const float* xb = x + (size_t)b * S_LEN;
    float xm = (s > 0) ? xb[s - 1] : 0.f;
    float x0 = xb[s];
    float xp = (s < S_LEN - 1) ? xb[s + 1] : 0.f;
    size_t base = ((size_t)(b * S_LEN + s)) * HCH + cch * 32;
#pragma unroll
    for (int cc = 0; cc < 4; ++cc) {
        short8 oh, ol;
#pragma unroll
        for (int e = 0; e < 8; ++e) {
            int co = cch * 32 + cc * 8 + e;
            float v = ws[co * 3 + 0] * xm + ws[co * 3 + 1] * x0 + ws[co * 3 + 2] * xp + bs[co];
            v = lrelu_f(v);
            short hi = f2bf(v);
            oh[e] = hi;
            ol[e] = f2bf(v - bf2f((unsigned short)hi));
        }
        *(short8*)(h_hi + base + cc * 8) = oh;
        *(short8*)(h_lo + base + cc * 8) = ol;
    }
}

// ---------------------------------------------------------------------------
// Encoder split-bf16 MFMA conv v3 (channels-last), k=3 SAME.
// K-chunk 64, X stride 68 shorts (bank-conflict-free, verified round 5:
// SQ_LDS_BANK_CONFLICT=0), weights from global/L2, wave-private epilogue
// (1 barrier).  NO min-waves bound: (256,4) forced 64 VGPR -> scratch
// spills -> 3.7x HBM traffic (round-5 regression). Natural ~156 unified
// regs -> 3 blocks/CU, no spills.
// ---------------------------------------------------------------------------
__global__ __launch_bounds__(256) void conv_mfma_split(
        const short* __restrict__ in_hi, const short* __restrict__ in_lo,
        short* __restrict__ out_hi, short* __restrict__ out_lo,
        const short* __restrict__ wt_hi, const short* __restrict__ wt_lo,
        const float* __restrict__ bias, int Cin, int Cout, int do_lrelu) {
    __shared__ short smem[17680];        // Xh[130][68] + Xl[130][68] = 35,360 B
    short* Xh = smem;
    short* Xl = smem + 130 * 68;

    const int tid = threadIdx.x;
    const int lane = tid & 63;
    const int w = tid >> 6;
    const int m = lane & 15;
    const int q = lane >> 4;
    const int sOff = (w & 1) * 64;
    const int cOff = (w >> 1) * 64;
    const int b = blockIdx.z;
    const int s0 = blockIdx.x * 128;
    const int co0 = blockIdx.y * 128;

    f32x4 acc[4][4];
    f32x4 zero4 = {0.f, 0.f, 0.f, 0.f};
#pragma unroll
    for (int i = 0; i < 4; ++i)
#pragma unroll
        for (int j = 0; j < 4; ++j) acc[i][j] = zero4;

    const short* inhb = in_hi + (size_t)b * S_LEN * Cin;
    const short* inlb = in_lo + (size_t)b * S_LEN * Cin;

    for (int ci0 = 0; ci0 < Cin; ci0 += 64) {
        __syncthreads();
        // X tile: rows s0-1 .. s0+128 (130) x 64 ci, hi+lo
        for (int c = tid; c < 2080; c += 256) {
            int r = c >> 4;
            int sub = c & 15;
            int half = sub >> 3;        // 0 = hi, 1 = lo
            int part = sub & 7;
            int s = s0 - 1 + r;
            float4 v = make_float4(0.f, 0.f, 0.f, 0.f);
            if (s >= 0 && s < S_LEN) {
                size_t goff = (size_t)s * Cin + ci0 + part * 8;
                v = half ? *(const float4*)(inlb + goff) : *(const float4*)(inhb + goff);
            }
            *(float4*)((half ? Xl : Xh) + r * 68 + part * 8) = v;
        }
        __syncthreads();

#pragma unroll
        for (int ks = 0; ks < 2; ++ks) {
            const int kofs = ks * 32;
#pragma unroll
            for (int t = 0; t < 3; ++t) {
                bf16x8 ah[4], al[4], bh[4], bl[4];
                // global (long-latency) loads first
#pragma unroll
                for (int j = 0; j < 4; ++j) {
                    size_t woff = ((size_t)(t * Cout + co0 + cOff + j * 16 + m)) * Cin + ci0 + kofs + q * 8;
                    bh[j] = *(const bf16x8*)(wt_hi + woff);
                    bl[j] = *(const bf16x8*)(wt_lo + woff);
                }
#pragma unroll
                for (int i = 0; i < 4; ++i) {
                    int row = sOff + i * 16 + m + t;
                    ah[i] = *(const bf16x8*)(Xh + row * 68 + kofs + q * 8);
                    al[i] = *(const bf16x8*)(Xl + row * 68 + kofs + q * 8);
                }
#pragma unroll
                for (int i = 0; i < 4; ++i)
#pragma unroll
                    for (int j = 0; j < 4; ++j) {
                        acc[i][j] = __builtin_amdgcn_mfma_f32_16x16x32_bf16(ah[i], bh[j], acc[i][j], 0, 0, 0);
                        acc[i][j] = __builtin_amdgcn_mfma_f32_16x16x32_bf16(ah[i], bl[j], acc[i][j], 0, 0, 0);
                        acc[i][j] = __builtin_amdgcn_mfma_f32_16x16x32_bf16(al[i], bh[j], acc[i][j], 0, 0, 0);
                    }
            }
        }
    }

    // Epilogue: one barrier, then wave-private LDS repack (no further syncs).
    __syncthreads();
    short* obH = smem + w * 2560;        // [64][20] hi
    short* obL = obH + 1280;             // [64][20] lo
#pragma unroll
    for (int j = 0; j < 4; ++j) {
        float bv = bias[co0 + cOff + j * 16 + m];
#pragma unroll
        for (int i = 0; i < 4; ++i) {
#pragma unroll
            for (int r = 0; r < 4; ++r) {
                float val = acc[i][j][r] + bv;
                if (do_lrelu) val = lrelu_f(val);
                short hi = f2bf(val);
                short lo = f2bf(val - bf2f((unsigned short)hi));
                int row = i * 16 + q * 4 + r;
                obH[row * 20 + m] = hi;
                obL[row * 20 + m] = lo;
            }
        }
        const int colchunk = lane & 1;
        const int rbase = lane >> 1;
#pragma unroll
        for (int it = 0; it < 2; ++it) {
            int row = it * 32 + rbase;
            short8 vh = *(const short8*)(obH + row * 20 + colchunk * 8);
            short8 vl = *(const short8*)(obL + row * 20 + colchunk * 8);
            size_t goff = ((size_t)(b * S_LEN + s0 + sOff + row)) * Cout
                        + co0 + cOff + j * 16 + colchunk * 8;
            *(short8*)(out_hi + goff) = vh;
            *(short8*)(out_lo + goff) = vl;
        }
    }
}

// ---------------------------------------------------------------------------
// VQ argmin via split-bf16 MFMA.  (unchanged)
// ---------------------------------------------------------------------------
__global__ __launch_bounds__(256) void vq_mfma_kernel(
        const short* __restrict__ z_hi, const short* __restrict__ z_lo,
        const short* __restrict__ cb_hi, const short* __restrict__ cb_lo,
        const float* __restrict__ cnorm, int* __restrict__ idx_out,
        float* __restrict__ idx_f_out) {
    __shared__ short smem[2 * 64 * 136];
    __shared__ float redv[64][4];
    __shared__ int   redi[64][4];
    short* Zh = smem;
    short* Zl = smem + 64 * 136;

    const int tid = threadIdx.x;
    const int lane = tid & 63;
    const int w = tid >> 6;
    const int m = lane & 15;
    const int q = lane >> 4;
    const int n0 = blockIdx.x * 64;

    for (int c = tid; c < 2048; c += 256) {
        int buf = c >> 10;
        int rem = c & 1023;
        int r = rem >> 4, part = rem & 15;
        size_t goff = (size_t)(n0 + r) * DCH + part * 8;
        float4 v = buf ? *(const float4*)(z_lo + goff) : *(const float4*)(z_hi + goff);
        *(float4*)((buf ? Zl : Zh) + r * 136 + part * 8) = v;
    }
    __syncthreads();

    float best[4][4];
    int besti[4][4];
#pragma unroll
    for (int i = 0; i < 4; ++i)
#pragma unroll
        for (int r = 0; r < 4; ++r) { best[i][r] = FLT_MAX; besti[i][r] = 0; }

    for (int k0 = 0; k0 < KCODES; k0 += 256) {
        f32x4 acc[4][4];
        f32x4 zero4 = {0.f, 0.f, 0.f, 0.f};
#pragma unroll
        for (int i = 0; i < 4; ++i)
#pragma unroll
            for (int j = 0; j < 4; ++j) acc[i][j] = zero4;

#pragma unroll
        for (int d0 = 0; d0 < DCH; d0 += 32) {
            bf16x8 ah[4], al[4], bh[4], bl[4];
#pragma unroll
            for (int j = 0; j < 4; ++j) {
                size_t coff = (size_t)(k0 + w * 64 + j * 16 + m) * DCH + d0 + q * 8;
                bh[j] = *(const bf16x8*)(cb_hi + coff);
                bl[j] = *(const bf16x8*)(cb_lo + coff);
            }
#pragma unroll
            for (int i = 0; i < 4; ++i) {
                int row = i * 16 + m;
                ah[i] = *(const bf16x8*)(Zh + row * 136 + d0 + q * 8);
                al[i] = *(const bf16x8*)(Zl + row * 136 + d0 + q * 8);
            }
#pragma unroll
            for (int i = 0; i < 4; ++i)
#pragma unroll
                for (int j = 0; j < 4; ++j) {
                    acc[i][j] = __builtin_amdgcn_mfma_f32_16x16x32_bf16(ah[i], bh[j], acc[i][j], 0, 0, 0);
                    acc[i][j] = __builtin_amdgcn_mfma_f32_16x16x32_bf16(ah[i], bl[j], acc[i][j], 0, 0, 0);
                    acc[i][j] = __builtin_amdgcn_mfma_f32_16x16x32_bf16(al[i], bh[j], acc[i][j], 0, 0, 0);
                }
        }
#pragma unroll
        for (int j = 0; j < 4; ++j) {
            int k = k0 + w * 64 + j * 16 + m;
            float cn = cnorm[k];
#pragma unroll
            for (int i = 0; i < 4; ++i)
#pragma unroll
                for (int r = 0; r < 4; ++r) {
                    float dv = cn - 2.f * acc[i][j][r];
                    if (dv < best[i][r]) { best[i][r] = dv; besti[i][r] = k; }
                }
        }
    }

#pragma unroll
    for (int mask = 1; mask < 16; mask <<= 1) {
#pragma unroll
        for (int i = 0; i < 4; ++i)
#pragma unroll
            for (int r = 0; r < 4; ++r) {
                float ov = __shfl_xor(best[i][r], mask);
                int oi = __shfl_xor(besti[i][r], mask);
                if (ov < best[i][r] || (ov == best[i][r] && oi < besti[i][r])) {
                    best[i][r] = ov; besti[i][r] = oi;
                }
            }
    }
    if (m == 0) {
#pragma unroll
        for (int i = 0; i < 4; ++i)
#pragma unroll
            for (int r = 0; r < 4; ++r) {
                int srow = i * 16 + q * 4 + r;
                redv[srow][w] = best[i][r];
                redi[srow][w] = besti[i][r];
            }
    }
    __syncthreads();
    if (tid < 64) {
        float bv = redv[tid][0];
        int bi = redi[tid][0];
#pragma unroll
        for (int w2 = 1; w2 < 4; ++w2) {
            float v = redv[tid][w2];
            int ii = redi[tid][w2];
            if (v < bv || (v == bv && ii < bi)) { bv = v; bi = ii; }
        }
        int n = n0 + tid;
        idx_out[n] = bi;
        idx_f_out[n] = (float)bi;
    }
}

// ---------------------------------------------------------------------------
// Fused gather + vq-sum: z_q bf16 [B][S][D] store + sum((z - cb[idx])^2).
// ---------------------------------------------------------------------------
__global__ __launch_bounds__(256) void gather_vqsum_kernel(
        const float* __restrict__ cb, const int* __restrict__ idxb,
        const short* __restrict__ z_hi, const short* __restrict__ z_lo,
        short* __restrict__ zq, float* __restrict__ acc_vq) {
    int tid = threadIdx.x;
    int b = blockIdx.y;
    int s = blockIdx.x * 32 + (tid >> 3);
    int dpart = tid & 7;
    int n = b * S_LEN + s;
    int k = idxb[n];
    const float* src = cb + (size_t)k * DCH + dpart * 16;
    size_t zoff = (size_t)n * DCH + dpart * 16;
    float sum = 0.f;
    short8 outv[2];
#pragma unroll
    for (int half = 0; half < 2; ++half) {
        float4 f0 = *(const float4*)(src + half * 8);
        float4 f1 = *(const float4*)(src + half * 8 + 4);
        bf16x8 zh = *(const bf16x8*)(z_hi + zoff + half * 8);
        bf16x8 zl = *(const bf16x8*)(z_lo + zoff + half * 8);
        float qv[8] = {f0.x, f0.y, f0.z, f0.w, f1.x, f1.y, f1.z, f1.w};
        short8 o;
#pragma unroll
        for (int e = 0; e < 8; ++e) {
            o[e] = f2bf(qv[e]);
            float zv = bf2f((unsigned short)zh[e]) + bf2f((unsigned short)zl[e]);
            float df = zv - qv[e];
            sum += df * df;
        }
        outv[half] = o;
    }
    *(short8*)(zq + zoff) = outv[0];
    *(short8*)(zq + zoff + 8) = outv[1];
    for (int off = 32; off > 0; off >>= 1) sum += __shfl_down(sum, off);
    __shared__ float wsum[4];
    if ((tid & 63) == 0) wsum[tid >> 6] = sum;
    __syncthreads();
    if (tid == 0) atomicAdd(acc_vq, wsum[0] + wsum[1] + wsum[2] + wsum[3]);
}

// ---------------------------------------------------------------------------
// Decoder bf16 MFMA conv v3 (channels-last): K-chunk 64, weights from
// global/L2, X stride 68, wave-private epilogue. Natural register alloc.
// ---------------------------------------------------------------------------
__global__ __launch_bounds__(256) void conv_mfma_cl(
        const short* __restrict__ in, short* __restrict__ out,
        const short* __restrict__ wt, const float* __restrict__ bias,
        int Cin) {
    __shared__ short smem[8840];         // Xs[130][68] = 17,680 B
    short* Xs = smem;

    const int tid = threadIdx.x;
    const int lane = tid & 63;
    const int w = tid >> 6;
    const int m = lane & 15;
    const int q = lane >> 4;
    const int sOff = (w & 1) * 64;
    const int cOff = (w >> 1) * 64;
    const int b = blockIdx.z;
    const int s0 = blockIdx.x * 128;
    const int co0 = blockIdx.y * 128;

    f32x4 acc[4][4];
    f32x4 zero4 = {0.f, 0.f, 0.f, 0.f};
#pragma unroll
    for (int i = 0; i < 4; ++i)
#pragma unroll
        for (int j = 0; j < 4; ++j) acc[i][j] = zero4;

    const short* inb = in + (size_t)b * S_LEN * Cin;

    for (int ci0 = 0; ci0 < Cin; ci0 += 64) {
        __syncthreads();
        for (int c = tid; c < 1040; c += 256) {
            int r = c >> 3;
            int part = c & 7;
            int s = s0 - 1 + r;
            float4 v = make_float4(0.f, 0.f, 0.f, 0.f);
            if (s >= 0 && s < S_LEN)
                v = *(const float4*)(inb + (size_t)s * Cin + ci0 + part * 8);
            *(float4*)(Xs + r * 68 + part * 8) = v;
        }
        __syncthreads();

#pragma unroll
        for (int ks = 0; ks < 2; ++ks) {
            const int kofs = ks * 32;
#pragma unroll
            for (int t = 0; t < 3; ++t) {
                bf16x8 a[4], bb[4];
#pragma unroll
                for (int j = 0; j < 4; ++j)
                    bb[j] = *(const bf16x8*)(wt + ((size_t)(t * 256 + co0 + cOff + j * 16 + m)) * Cin + ci0 + kofs + q * 8);
#pragma unroll
                for (int i = 0; i < 4; ++i)
                    a[i] = *(const bf16x8*)(Xs + (sOff + i * 16 + m + t) * 68 + kofs + q * 8);
#pragma unroll
                for (int i = 0; i < 4; ++i)
#pragma unroll
                    for (int j = 0; j < 4; ++j)
                        acc[i][j] = __builtin_amdgcn_mfma_f32_16x16x32_bf16(
                            a[i], bb[j], acc[i][j], 0, 0, 0);
            }
        }
    }

    __syncthreads();
    short* ob = smem + w * 1280;         // [64][20], wave-private
#pragma unroll
    for (int j = 0; j < 4; ++j) {
        float bv = bias[co0 + cOff + j * 16 + m];
#pragma unroll
        for (int i = 0; i < 4; ++i) {
#pragma unroll
            for (int r = 0; r < 4; ++r) {
                float val = acc[i][j][r] + bv;
                val = lrelu_f(val);
                ob[(i * 16 + q * 4 + r) * 20 + m] = f2bf(val);
            }
        }
        const int colchunk = lane & 1;
        const int rbase = lane >> 1;
#pragma unroll
        for (int it = 0; it < 2; ++it) {
            int row = it * 32 + rbase;
            short8 v = *(const short8*)(ob + row * 20 + colchunk * 8);
            size_t goff = ((size_t)(b * S_LEN + s0 + sOff + row)) * 256
                        + co0 + cOff + j * 16 + colchunk * 8;
            *(short8*)(out + goff) = v;
        }
    }
}

// ---------------------------------------------------------------------------
// Decoder conv3, LDS-tiled (unchanged).
// ---------------------------------------------------------------------------
__global__ __launch_bounds__(256) void dec_conv3_tiled_kernel(
        const short* __restrict__ h, const float* __restrict__ w3t,
        const float* __restrict__ b3, const float* __restrict__ x,
        float* __restrict__ xr, float* __restrict__ acc_recon) {
    __shared__ short Zs[66 * 264];
    __shared__ float ws[3 * 256];
    __shared__ float wsum[4];
    int tid = threadIdx.x;
    int b = blockIdx.y;
    int s0 = blockIdx.x * 64;
    const short* hb = h + (size_t)b * S_LEN * HCH;
    for (int i = tid; i < 768; i += 256) ws[i] = w3t[i];
    for (int c = tid; c < 2112; c += 256) {
        int r = c >> 5, part = c & 31;
        int g = s0 - 1 + r;
        short8 v = {0, 0, 0, 0, 0, 0, 0, 0};
        if (g >= 0 && g < S_LEN)
            v = *(const short8*)(hb + (size_t)g * HCH + part * 8);
        *(short8*)(Zs + r * 264 + part * 8) = v;
    }
    __syncthreads();

    int quarter = tid & 3;
    int sl = tid >> 2;
    float a0 = 0.f, a1 = 0.f, a2 = 0.f, a3 = 0.f;
#pragma unroll
    for (int t = 0; t < 3; ++t) {
        const short* zrow = Zs + (sl + t) * 264 + quarter * 64;
        const float* wrow = ws + t * 256 + quarter * 64;
#pragma unroll
        for (int c = 0; c < 8; ++c) {
            bf16x8 v = *(const bf16x8*)(zrow + c * 8);
            float4 w0 = *(const float4*)(wrow + c * 8);
            float4 w1 = *(const float4*)(wrow + c * 8 + 4);
            a0 = fmaf(w0.x, bf2f((unsigned short)v[0]), a0);
            a1 = fmaf(w0.y, bf2f((unsigned short)v[1]), a1);
            a2 = fmaf(w0.z, bf2f((unsigned short)v[2]), a2);
            a3 = fmaf(w0.w, bf2f((unsigned short)v[3]), a3);
            a0 = fmaf(w1.x, bf2f((unsigned short)v[4]), a0);
            a1 = fmaf(w1.y, bf2f((unsigned short)v[5]), a1);
            a2 = fmaf(w1.z, bf2f((unsigned short)v[6]), a2);
            a3 = fmaf(w1.w, bf2f((unsigned short)v[7]), a3);
        }
    }
    float acc = (a0 + a1) + (a2 + a3);
    acc += __shfl_xor(acc, 1);
    acc += __shfl_xor(acc, 2);
    float df2 = 0.f;
    if (quarter == 0) {
        int s = s0 + sl;
        float tot = acc + b3[0];
        xr[b * S_LEN + s] = tot;
        float df = x[b * S_LEN + s] - tot;
        df2 = df * df;
    }
    for (int off = 32; off > 0; off >>= 1) df2 += __shfl_down(df2, off);
    int lane = tid & 63, wv = tid >> 6;
    if (lane == 0) wsum[wv] = df2;
    __syncthreads();
    if (tid == 0) atomicAdd(acc_recon, wsum[0] + wsum[1] + wsum[2] + wsum[3]);
}

// ---------------------------------------------------------------------------
__global__ void finalize_kernel(const float* __restrict__ accs, float* __restrict__ out) {
    if (threadIdx.x == 0) {
        float vqm = accs[0] / ((float)BATCH * S_LEN * DCH);
        float rm  = accs[1] / ((float)BATCH * S_LEN);
        float vq_loss = vqm * 0.05f;
        float commit  = vqm * 0.15f;
        float recon   = rm * 1.0f;
        out[0] = recon + vq_loss + commit;
        out[1] = recon;
        out[2] = vq_loss;
        out[3] = commit;
    }
}

// ---------------------------------------------------------------------------
extern "C" void kernel_launch(void* const* d_in, const int* in_sizes, int n_in,
                              void* d_out, int out_size, void* d_ws, size_t ws_size,
                              hipStream_t stream) {
    const float* x    = (const float*)d_in[0];
    const float* cb   = (const float*)d_in[1];
    const float* ew1  = (const float*)d_in[2];
    const float* eb1  = (const float*)d_in[3];
    const float* ew2  = (const float*)d_in[4];
    const float* eb2  = (const float*)d_in[5];
    const float* ew3  = (const float*)d_in[6];
    const float* eb3  = (const float*)d_in[7];
    const float* dw1  = (const float*)d_in[8];
    const float* db1  = (const float*)d_in[9];
    const float* dw2  = (const float*)d_in[10];
    const float* db2  = (const float*)d_in[11];
    const float* dw3  = (const float*)d_in[12];
    const float* db3  = (const float*)d_in[13];

    float* out = (float*)d_out;
    float* xr    = out;
    float* idx_f = out + BATCH * S_LEN;
    float* loss_out = out + 2 * BATCH * S_LEN;

    const size_t NH = (size_t)BATCH * S_LEN * HCH;   // 16,777,216
    const size_t ND = (size_t)BATCH * S_LEN * DCH;   // 8,388,608

    short* sp = (short*)d_ws;
    short* h1_hi = sp;
    short* h1_lo = sp + NH;
    short* z_hi  = sp;            // overlays h1 (dead after conv2)
    short* z_lo  = sp + ND;
    short* h1d_bf = sp;           // overlays z (dead after vq+gather_vqsum)
    short* h2_hi = sp + 2 * NH;
    short* h2_lo = sp + 3 * NH;
    short* zq_bf = sp + 2 * NH;   // overlays h2 (dead after conv3)
    short* h2d_bf = sp + 3 * NH;
    short* sm = sp + 4 * NH;
    short* cb_hi = sm; sm += KCODES * DCH;
    short* cb_lo = sm; sm += KCODES * DCH;
    short* w2_hi = sm; sm += 3 * HCH * HCH;
    short* w2_lo = sm; sm += 3 * HCH * HCH;
    short* w3_hi = sm; sm += 3 * DCH * HCH;
    short* w3_lo = sm; sm += 3 * DCH * HCH;
    short* wbf_d1 = sm; sm += 3 * 256 * DCH;
    short* wbf_d2 = sm; sm += 3 * 256 * HCH;
    float* cnorm = (float*)sm;
    int* idxb = (int*)(cnorm + KCODES);
    float* w3t = (float*)(idxb + BATCH * S_LEN);
    float* accs = w3t + 768;

    hipMemsetAsync(accs, 0, 2 * sizeof(float), stream);

    // prep
    prep_cb_split_kernel<<<2, 256, 0, stream>>>(cb, cb_hi, cb_lo, cnorm);
    prep_w_split_kernel<<<(3 * HCH * HCH + 255) / 256, 256, 0, stream>>>(ew2, w2_hi, w2_lo, HCH, HCH);
    prep_w_split_kernel<<<(3 * DCH * HCH + 255) / 256, 256, 0, stream>>>(ew3, w3_hi, w3_lo, DCH, HCH);
    prep_wdec_kernel<<<(3 * 256 * DCH + 255) / 256, 256, 0, stream>>>(dw1, wbf_d1, DCH);
    prep_wdec_kernel<<<(3 * 256 * HCH + 255) / 256, 256, 0, stream>>>(dw2, wbf_d2, HCH);
    prep_w3t_kernel<<<3, 256, 0, stream>>>(dw3, w3t);

    // encoder (split-bf16 MFMA)
    enc_conv1_cl_kernel<<<dim3(S_LEN / 32, BATCH), 256, 0, stream>>>(x, h1_hi, h1_lo, ew1, eb1);
    conv_mfma_split<<<dim3(S_LEN / 128, HCH / 128, BATCH), 256, 0, stream>>>(
        h1_hi, h1_lo, h2_hi, h2_lo, w2_hi, w2_lo, eb2, HCH, HCH, 1);
    conv_mfma_split<<<dim3(S_LEN / 128, DCH / 128, BATCH), 256, 0, stream>>>(
        h2_hi, h2_lo, z_hi, z_lo, w3_hi, w3_lo, eb3, HCH, DCH, 0);

    // VQ
    vq_mfma_kernel<<<(BATCH * S_LEN) / 64, 256, 0, stream>>>(
        z_hi, z_lo, cb_hi, cb_lo, cnorm, idxb, idx_f);
    gather_vqsum_kernel<<<dim3(S_LEN / 32, BATCH), 256, 0, stream>>>(
        cb, idxb, z_hi, z_lo, zq_bf, accs);

    // decoder (bf16 MFMA)
    conv_mfma_cl<<<dim3(S_LEN / 128, 2, BATCH), 256, 0, stream>>>(
        zq_bf, h1d_bf, wbf_d1, db1, DCH);
    conv_mfma_cl<<<dim3(S_LEN / 128, 2, BATCH), 256, 0, stream>>>(
        h1d_bf, h2d_bf, wbf_d2, db2, HCH);
    dec_conv3_tiled_kernel<<<dim3(S_LEN / 64, BATCH), 256, 0, stream>>>(
        h2d_bf, w3t, db3, x, xr, accs + 1);

    finalize_kernel<<<1, 64, 0, stream>>>(accs, loss_out);
}

// Round 7
// 527.624 us; speedup vs baseline: 1.2432x; 1.0788x over previous
//
#include <hip/hip_runtime.h>
#include <float.h>

// Problem constants
#define S_LEN 2048
#define BATCH 32
#define HCH   256
#define DCH   128
#define KCODES 512

typedef float  f32x4  __attribute__((ext_vector_type(4)));
typedef short  bf16x8 __attribute__((ext_vector_type(8)));
typedef short  short8 __attribute__((ext_vector_type(8)));

__device__ __forceinline__ float lrelu_f(float v) { return v >= 0.f ? v : 0.2f * v; }

// fp32 -> bf16 bits, round-to-nearest-even (finite values)
__device__ __forceinline__ short f2bf(float f) {
    unsigned u = __float_as_uint(f);
    u = u + 0x7fffu + ((u >> 16) & 1u);
    return (short)(u >> 16);
}
__device__ __forceinline__ float bf2f(unsigned short u) {
    return __uint_as_float(((unsigned)u) << 16);
}

// ---------------------------------------------------------------------------
// Codebook prep: cb[K][D] fp32 -> cb_hi/cb_lo bf16 [K][D], cnorm fp32
// ---------------------------------------------------------------------------
__global__ void prep_cb_split_kernel(const float* __restrict__ cb,
                                     short* __restrict__ cb_hi, short* __restrict__ cb_lo,
                                     float* __restrict__ cnorm) {
    int k = blockIdx.x * 256 + threadIdx.x;
    if (k < KCODES) {
        float s = 0.f;
        for (int d = 0; d < DCH; ++d) {
            float v = cb[k * DCH + d];
            s += v * v;
            short hi = f2bf(v);
            short lo = f2bf(v - bf2f((unsigned short)hi));
            cb_hi[k * DCH + d] = hi;
            cb_lo[k * DCH + d] = lo;
        }
        cnorm[k] = s;
    }
}

// ---------------------------------------------------------------------------
// Encoder weight prep: W[Cout][Cin][3] fp32 -> [3][Cout][Cin] bf16 hi/lo
// ---------------------------------------------------------------------------
__global__ void prep_w_split_kernel(const float* __restrict__ Wsrc,
                                    short* __restrict__ Wh, short* __restrict__ Wl,
                                    int Cout, int Cin) {
    int i = blockIdx.x * 256 + threadIdx.x;
    int total = 3 * Cout * Cin;
    if (i < total) {
        int t = i / (Cout * Cin);
        int rem = i - t * Cout * Cin;
        int co = rem / Cin;
        int ci = rem - co * Cin;
        float v = Wsrc[(co * Cin + ci) * 3 + t];
        short hi = f2bf(v);
        Wh[i] = hi;
        Wl[i] = f2bf(v - bf2f((unsigned short)hi));
    }
}

// ---------------------------------------------------------------------------
// Decoder weight prep: dw[Cout=256][Cin][3] fp32 -> wt[3][256][Cin] bf16
// ---------------------------------------------------------------------------
__global__ void prep_wdec_kernel(const float* __restrict__ Wsrc, short* __restrict__ Wdst,
                                 int Cin) {
    int i = blockIdx.x * 256 + threadIdx.x;
    int total = 3 * 256 * Cin;
    if (i < total) {
        int t = i / (256 * Cin);
        int rem = i - t * 256 * Cin;
        int co = rem / Cin;
        int ci = rem - co * Cin;
        Wdst[i] = f2bf(Wsrc[(co * Cin + ci) * 3 + t]);
    }
}

// ---------------------------------------------------------------------------
// Decoder conv3 weight repack: dw3[ci*3+t] fp32 -> w3t[t*256+ci] fp32
// ---------------------------------------------------------------------------
__global__ void prep_w3t_kernel(const float* __restrict__ w3, float* __restrict__ w3t) {
    int i = blockIdx.x * 256 + threadIdx.x;
    if (i < 768) {
        int t = i / 256, ci = i - t * 256;
        w3t[i] = w3[ci * 3 + t];
    }
}

// ---------------------------------------------------------------------------
// Encoder conv1 channels-last: x[B][S] -> h hi/lo bf16 [B][S][256], lrelu.
// ---------------------------------------------------------------------------
__global__ __launch_bounds__(256) void enc_conv1_cl_kernel(
        const float* __restrict__ x, short* __restrict__ h_hi, short* __restrict__ h_lo,
        const float* __restrict__ w, const float* __restrict__ bias) {
    __shared__ float ws[HCH * 3];
    __shared__ float bs[HCH];
    int tid = threadIdx.x;
    for (int i = tid; i < HCH * 3; i += 256) ws[i] = w[i];
    for (int i = tid; i < HCH; i += 256) bs[i] = bias[i];
    __syncthreads();
    int b = blockIdx.y;
    int s = blockIdx.x * 32 + (tid >> 3);
    int cch = tid & 7;
    const float* xb = x + (size_t)b * S_LEN;
    float xm = (s > 0) ? xb[s - 1] : 0.f;
    float x0 = xb[s];
    float xp = (s < S_LEN - 1) ? xb[s + 1] : 0.f;
    size_t base = ((size_t)(b * S_LEN + s)) * HCH + cch * 32;
#pragma unroll
    for (int cc = 0; cc < 4; ++cc) {
        short8 oh, ol;
#pragma unroll
        for (int e = 0; e < 8; ++e) {
            int co = cch * 32 + cc * 8 + e;
            float v = ws[co * 3 + 0] * xm + ws[co * 3 + 1] * x0 + ws[co * 3 + 2] * xp + bs[co];
            v = lrelu_f(v);
            short hi = f2bf(v);
            oh[e] = hi;
            ol[e] = f2bf(v - bf2f((unsigned short)hi));
        }
        *(short8*)(h_hi + base + cc * 8) = oh;
        *(short8*)(h_lo + base + cc * 8) = ol;
    }
}

// ---------------------------------------------------------------------------
// Encoder split-bf16 MFMA conv v4: register-prefetch + double-buffered LDS.
// K-chunk 32; X stride 40 shorts (16B-aligned rows, 2-way bank alias = free);
// weights from global/L2; one barrier per K-chunk with no vmcnt drain
// (prefetch issued after barrier, consumed by LDS write next iteration).
// Natural register alloc (~104 arch + 64 acc -> 3 waves/SIMD). Round-5
// lesson: do NOT set min-waves bound (spills).
// ---------------------------------------------------------------------------
__global__ __launch_bounds__(256) void conv_mfma_split(
        const short* __restrict__ in_hi, const short* __restrict__ in_lo,
        short* __restrict__ out_hi, short* __restrict__ out_lo,
        const short* __restrict__ wt_hi, const short* __restrict__ wt_lo,
        const float* __restrict__ bias, int Cin, int Cout, int do_lrelu) {
    __shared__ short smem[20800];   // 2 buffers x (Xh[130][40] + Xl[130][40]) = 41.6 KB

    const int tid = threadIdx.x;
    const int lane = tid & 63;
    const int w = tid >> 6;
    const int m = lane & 15;
    const int q = lane >> 4;
    const int sOff = (w & 1) * 64;
    const int cOff = (w >> 1) * 64;
    const int b = blockIdx.z;
    const int s0 = blockIdx.x * 128;
    const int co0 = blockIdx.y * 128;

    f32x4 acc[4][4];
    f32x4 zero4 = {0.f, 0.f, 0.f, 0.f};
#pragma unroll
    for (int i = 0; i < 4; ++i)
#pragma unroll
        for (int j = 0; j < 4; ++j) acc[i][j] = zero4;

    // --- staging geometry (constant per thread) ---
    // main: 128 rows x (4 ci-parts x 2 halves) = 1024 items = 4/thread
    // halo: rows 0 and 129, 16 items, threads 0..15
    const int half = (tid >> 2) & 1;            // 0 = hi, 1 = lo
    const int p8 = (tid & 3) * 8;               // ci sub-offset (shorts)
    const int srow = tid >> 3;                  // 0..31
    const short* gsrc = half ? (in_lo + (size_t)b * S_LEN * Cin)
                             : (in_hi + (size_t)b * S_LEN * Cin);
    const short* gptr = gsrc + (size_t)(s0 + srow) * Cin + p8;
    const int hs = (tid >> 3) ? (s0 + 128) : (s0 - 1);     // halo s (threads<16)
    const bool hvalid = (tid < 16) && hs >= 0 && hs < S_LEN;
    const short* hptr = gsrc + (size_t)(hvalid ? hs : 0) * Cin + p8;
    const int hrow = (tid >> 3) ? 129 : 0;
    const size_t cstride = (size_t)32 * Cin;

    float4 pf0, pf1, pf2, pf3, ph;

#define ENC_PREFETCH(CI0) do {                                              \
    pf0 = *(const float4*)(gptr + (CI0));                                   \
    pf1 = *(const float4*)(gptr + cstride + (CI0));                         \
    pf2 = *(const float4*)(gptr + 2 * cstride + (CI0));                     \
    pf3 = *(const float4*)(gptr + 3 * cstride + (CI0));                     \
    ph = make_float4(0.f, 0.f, 0.f, 0.f);                                   \
    if (hvalid) ph = *(const float4*)(hptr + (CI0)); } while (0)

#define ENC_WRITEBUF(BUF) do {                                              \
    short* dst = smem + (BUF) * 10400 + half * 5200 + (srow + 1) * 40 + p8; \
    *(float4*)dst = pf0;                                                    \
    *(float4*)(dst + 32 * 40) = pf1;                                        \
    *(float4*)(dst + 64 * 40) = pf2;                                        \
    *(float4*)(dst + 96 * 40) = pf3;                                        \
    if (tid < 16)                                                           \
        *(float4*)(smem + (BUF) * 10400 + half * 5200 + hrow * 40 + p8) = ph; } while (0)

    const int NC = Cin >> 5;                    // K-chunks of 32

    ENC_PREFETCH(0);
    ENC_WRITEBUF(0);
    __syncthreads();
    if (NC > 1) ENC_PREFETCH(32);

    for (int c = 0; c < NC; ++c) {
        const short* Xh = smem + (c & 1) * 10400;
        const short* Xl = Xh + 5200;
        const int ci0 = c * 32;
#pragma unroll
        for (int t = 0; t < 3; ++t) {
            bf16x8 ah[4], al[4], bh[4], bl[4];
            // global (long-latency) weight loads first
#pragma unroll
            for (int j = 0; j < 4; ++j) {
                size_t woff = ((size_t)(t * Cout + co0 + cOff + j * 16 + m)) * Cin + ci0 + q * 8;
                bh[j] = *(const bf16x8*)(wt_hi + woff);
                bl[j] = *(const bf16x8*)(wt_lo + woff);
            }
#pragma unroll
            for (int i = 0; i < 4; ++i) {
                int row = sOff + i * 16 + m + t;
                ah[i] = *(const bf16x8*)(Xh + row * 40 + q * 8);
                al[i] = *(const bf16x8*)(Xl + row * 40 + q * 8);
            }
#pragma unroll
            for (int i = 0; i < 4; ++i)
#pragma unroll
                for (int j = 0; j < 4; ++j) {
                    acc[i][j] = __builtin_amdgcn_mfma_f32_16x16x32_bf16(ah[i], bh[j], acc[i][j], 0, 0, 0);
                    acc[i][j] = __builtin_amdgcn_mfma_f32_16x16x32_bf16(ah[i], bl[j], acc[i][j], 0, 0, 0);
                    acc[i][j] = __builtin_amdgcn_mfma_f32_16x16x32_bf16(al[i], bh[j], acc[i][j], 0, 0, 0);
                }
        }
        if (c + 1 < NC) {
            ENC_WRITEBUF((c + 1) & 1);          // vmcnt wait for prefetched regs lands here
            __syncthreads();
            if (c + 2 < NC) ENC_PREFETCH((c + 2) * 32);
        }
    }

    // Epilogue: one barrier, then wave-private LDS repack (no further syncs).
    __syncthreads();
    short* obH = smem + w * 2560;        // [64][20] hi
    short* obL = obH + 1280;             // [64][20] lo
#pragma unroll
    for (int j = 0; j < 4; ++j) {
        float bv = bias[co0 + cOff + j * 16 + m];
#pragma unroll
        for (int i = 0; i < 4; ++i) {
#pragma unroll
            for (int r = 0; r < 4; ++r) {
                float val = acc[i][j][r] + bv;
                if (do_lrelu) val = lrelu_f(val);
                short hi = f2bf(val);
                short lo = f2bf(val - bf2f((unsigned short)hi));
                int row = i * 16 + q * 4 + r;
                obH[row * 20 + m] = hi;
                obL[row * 20 + m] = lo;
            }
        }
        const int colchunk = lane & 1;
        const int rbase = lane >> 1;
#pragma unroll
        for (int it = 0; it < 2; ++it) {
            int row = it * 32 + rbase;
            short8 vh = *(const short8*)(obH + row * 20 + colchunk * 8);
            short8 vl = *(const short8*)(obL + row * 20 + colchunk * 8);
            size_t goff = ((size_t)(b * S_LEN + s0 + sOff + row)) * Cout
                        + co0 + cOff + j * 16 + colchunk * 8;
            *(short8*)(out_hi + goff) = vh;
            *(short8*)(out_lo + goff) = vl;
        }
    }
#undef ENC_PREFETCH
#undef ENC_WRITEBUF
}

// ---------------------------------------------------------------------------
// VQ argmin via split-bf16 MFMA.  (unchanged)
// ---------------------------------------------------------------------------
__global__ __launch_bounds__(256) void vq_mfma_kernel(
        const short* __restrict__ z_hi, const short* __restrict__ z_lo,
        const short* __restrict__ cb_hi, const short* __restrict__ cb_lo,
        const float* __restrict__ cnorm, int* __restrict__ idx_out,
        float* __restrict__ idx_f_out) {
    __shared__ short smem[2 * 64 * 136];
    __shared__ float redv[64][4];
    __shared__ int   redi[64][4];
    short* Zh = smem;
    short* Zl = smem + 64 * 136;

    const int tid = threadIdx.x;
    const int lane = tid & 63;
    const int w = tid >> 6;
    const int m = lane & 15;
    const int q = lane >> 4;
    const int n0 = blockIdx.x * 64;

    for (int c = tid; c < 2048; c += 256) {
        int buf = c >> 10;
        int rem = c & 1023;
        int r = rem >> 4, part = rem & 15;
        size_t goff = (size_t)(n0 + r) * DCH + part * 8;
        float4 v = buf ? *(const float4*)(z_lo + goff) : *(const float4*)(z_hi + goff);
        *(float4*)((buf ? Zl : Zh) + r * 136 + part * 8) = v;
    }
    __syncthreads();

    float best[4][4];
    int besti[4][4];
#pragma unroll
    for (int i = 0; i < 4; ++i)
#pragma unroll
        for (int r = 0; r < 4; ++r) { best[i][r] = FLT_MAX; besti[i][r] = 0; }

    for (int k0 = 0; k0 < KCODES; k0 += 256) {
        f32x4 acc[4][4];
        f32x4 zero4 = {0.f, 0.f, 0.f, 0.f};
#pragma unroll
        for (int i = 0; i < 4; ++i)
#pragma unroll
            for (int j = 0; j < 4; ++j) acc[i][j] = zero4;

#pragma unroll
        for (int d0 = 0; d0 < DCH; d0 += 32) {
            bf16x8 ah[4], al[4], bh[4], bl[4];
#pragma unroll
            for (int j = 0; j < 4; ++j) {
                size_t coff = (size_t)(k0 + w * 64 + j * 16 + m) * DCH + d0 + q * 8;
                bh[j] = *(const bf16x8*)(cb_hi + coff);
                bl[j] = *(const bf16x8*)(cb_lo + coff);
            }
#pragma unroll
            for (int i = 0; i < 4; ++i) {
                int row = i * 16 + m;
                ah[i] = *(const bf16x8*)(Zh + row * 136 + d0 + q * 8);
                al[i] = *(const bf16x8*)(Zl + row * 136 + d0 + q * 8);
            }
#pragma unroll
            for (int i = 0; i < 4; ++i)
#pragma unroll
                for (int j = 0; j < 4; ++j) {
                    acc[i][j] = __builtin_amdgcn_mfma_f32_16x16x32_bf16(ah[i], bh[j], acc[i][j], 0, 0, 0);
                    acc[i][j] = __builtin_amdgcn_mfma_f32_16x16x32_bf16(ah[i], bl[j], acc[i][j], 0, 0, 0);
                    acc[i][j] = __builtin_amdgcn_mfma_f32_16x16x32_bf16(al[i], bh[j], acc[i][j], 0, 0, 0);
                }
        }
#pragma unroll
        for (int j = 0; j < 4; ++j) {
            int k = k0 + w * 64 + j * 16 + m;
            float cn = cnorm[k];
#pragma unroll
            for (int i = 0; i < 4; ++i)
#pragma unroll
                for (int r = 0; r < 4; ++r) {
                    float dv = cn - 2.f * acc[i][j][r];
                    if (dv < best[i][r]) { best[i][r] = dv; besti[i][r] = k; }
                }
        }
    }

#pragma unroll
    for (int mask = 1; mask < 16; mask <<= 1) {
#pragma unroll
        for (int i = 0; i < 4; ++i)
#pragma unroll
            for (int r = 0; r < 4; ++r) {
                float ov = __shfl_xor(best[i][r], mask);
                int oi = __shfl_xor(besti[i][r], mask);
                if (ov < best[i][r] || (ov == best[i][r] && oi < besti[i][r])) {
                    best[i][r] = ov; besti[i][r] = oi;
                }
            }
    }
    if (m == 0) {
#pragma unroll
        for (int i = 0; i < 4; ++i)
#pragma unroll
            for (int r = 0; r < 4; ++r) {
                int srow = i * 16 + q * 4 + r;
                redv[srow][w] = best[i][r];
                redi[srow][w] = besti[i][r];
            }
    }
    __syncthreads();
    if (tid < 64) {
        float bv = redv[tid][0];
        int bi = redi[tid][0];
#pragma unroll
        for (int w2 = 1; w2 < 4; ++w2) {
            float v = redv[tid][w2];
            int ii = redi[tid][w2];
            if (v < bv || (v == bv && ii < bi)) { bv = v; bi = ii; }
        }
        int n = n0 + tid;
        idx_out[n] = bi;
        idx_f_out[n] = (float)bi;
    }
}

// ---------------------------------------------------------------------------
// Fused gather + vq-sum: z_q bf16 [B][S][D] store + sum((z - cb[idx])^2).
// ---------------------------------------------------------------------------
__global__ __launch_bounds__(256) void gather_vqsum_kernel(
        const float* __restrict__ cb, const int* __restrict__ idxb,
        const short* __restrict__ z_hi, const short* __restrict__ z_lo,
        short* __restrict__ zq, float* __restrict__ acc_vq) {
    int tid = threadIdx.x;
    int b = blockIdx.y;
    int s = blockIdx.x * 32 + (tid >> 3);
    int dpart = tid & 7;
    int n = b * S_LEN + s;
    int k = idxb[n];
    const float* src = cb + (size_t)k * DCH + dpart * 16;
    size_t zoff = (size_t)n * DCH + dpart * 16;
    float sum = 0.f;
    short8 outv[2];
#pragma unroll
    for (int half = 0; half < 2; ++half) {
        float4 f0 = *(const float4*)(src + half * 8);
        float4 f1 = *(const float4*)(src + half * 8 + 4);
        bf16x8 zh = *(const bf16x8*)(z_hi + zoff + half * 8);
        bf16x8 zl = *(const bf16x8*)(z_lo + zoff + half * 8);
        float qv[8] = {f0.x, f0.y, f0.z, f0.w, f1.x, f1.y, f1.z, f1.w};
        short8 o;
#pragma unroll
        for (int e = 0; e < 8; ++e) {
            o[e] = f2bf(qv[e]);
            float zv = bf2f((unsigned short)zh[e]) + bf2f((unsigned short)zl[e]);
            float df = zv - qv[e];
            sum += df * df;
        }
        outv[half] = o;
    }
    *(short8*)(zq + zoff) = outv[0];
    *(short8*)(zq + zoff + 8) = outv[1];
    for (int off = 32; off > 0; off >>= 1) sum += __shfl_down(sum, off);
    __shared__ float wsum[4];
    if ((tid & 63) == 0) wsum[tid >> 6] = sum;
    __syncthreads();
    if (tid == 0) atomicAdd(acc_vq, wsum[0] + wsum[1] + wsum[2] + wsum[3]);
}

// ---------------------------------------------------------------------------
// Decoder bf16 MFMA conv v4: register-prefetch + double-buffered LDS,
// K-chunk 32, stride 40, weights from global/L2, wave-private epilogue.
// ---------------------------------------------------------------------------
__global__ __launch_bounds__(256) void conv_mfma_cl(
        const short* __restrict__ in, short* __restrict__ out,
        const short* __restrict__ wt, const float* __restrict__ bias,
        int Cin) {
    __shared__ short smem[10400];   // 2 buffers x Xs[130][40] = 20.8 KB

    const int tid = threadIdx.x;
    const int lane = tid & 63;
    const int w = tid >> 6;
    const int m = lane & 15;
    const int q = lane >> 4;
    const int sOff = (w & 1) * 64;
    const int cOff = (w >> 1) * 64;
    const int b = blockIdx.z;
    const int s0 = blockIdx.x * 128;
    const int co0 = blockIdx.y * 128;

    f32x4 acc[4][4];
    f32x4 zero4 = {0.f, 0.f, 0.f, 0.f};
#pragma unroll
    for (int i = 0; i < 4; ++i)
#pragma unroll
        for (int j = 0; j < 4; ++j) acc[i][j] = zero4;

    // staging: main 128 rows x 4 parts = 512 items = 2/thread; halo 8 items
    const int p8 = (tid & 3) * 8;
    const int srow = tid >> 2;                  // 0..63
    const short* gsrc = in + (size_t)b * S_LEN * Cin;
    const short* gptr = gsrc + (size_t)(s0 + srow) * Cin + p8;
    const int hs = (tid >> 2) ? (s0 + 128) : (s0 - 1);   // threads<8
    const bool hvalid = (tid < 8) && hs >= 0 && hs < S_LEN;
    const short* hptr = gsrc + (size_t)(hvalid ? hs : 0) * Cin + p8;
    const int hrow = (tid >> 2) ? 129 : 0;
    const size_t cstride = (size_t)64 * Cin;

    float4 pf0, pf1, ph;

#define DEC_PREFETCH(CI0) do {                                              \
    pf0 = *(const float4*)(gptr + (CI0));                                   \
    pf1 = *(const float4*)(gptr + cstride + (CI0));                         \
    ph = make_float4(0.f, 0.f, 0.f, 0.f);                                   \
    if (hvalid) ph = *(const float4*)(hptr + (CI0)); } while (0)

#define DEC_WRITEBUF(BUF) do {                                              \
    short* dst = smem + (BUF) * 5200 + (srow + 1) * 40 + p8;                \
    *(float4*)dst = pf0;                                                    \
    *(float4*)(dst + 64 * 40) = pf1;                                        \
    if (tid < 8)                                                            \
        *(float4*)(smem + (BUF) * 5200 + hrow * 40 + p8) = ph; } while (0)

    const int NC = Cin >> 5;

    DEC_PREFETCH(0);
    DEC_WRITEBUF(0);
    __syncthreads();
    if (NC > 1) DEC_PREFETCH(32);

    for (int c = 0; c < NC; ++c) {
        const short* Xs = smem + (c & 1) * 5200;
        const int ci0 = c * 32;
#pragma unroll
        for (int t = 0; t < 3; ++t) {
            bf16x8 a[4], bb[4];
#pragma unroll
            for (int j = 0; j < 4; ++j)
                bb[j] = *(const bf16x8*)(wt + ((size_t)(t * 256 + co0 + cOff + j * 16 + m)) * Cin + ci0 + q * 8);
#pragma unroll
            for (int i = 0; i < 4; ++i)
                a[i] = *(const bf16x8*)(Xs + (sOff + i * 16 + m + t) * 40 + q * 8);
#pragma unroll
            for (int i = 0; i < 4; ++i)
#pragma unroll
                for (int j = 0; j < 4; ++j)
                    acc[i][j] = __builtin_amdgcn_mfma_f32_16x16x32_bf16(
                        a[i], bb[j], acc[i][j], 0, 0, 0);
        }
        if (c + 1 < NC) {
            DEC_WRITEBUF((c + 1) & 1);
            __syncthreads();
            if (c + 2 < NC) DEC_PREFETCH((c + 2) * 32);
        }
    }

    __syncthreads();
    short* ob = smem + w * 1280;         // [64][20], wave-private
#pragma unroll
    for (int j = 0; j < 4; ++j) {
        float bv = bias[co0 + cOff + j * 16 + m];
#pragma unroll
        for (int i = 0; i < 4; ++i) {
#pragma unroll
            for (int r = 0; r < 4; ++r) {
                float val = acc[i][j][r] + bv;
                val = lrelu_f(val);
                ob[(i * 16 + q * 4 + r) * 20 + m] = f2bf(val);
            }
        }
        const int colchunk = lane & 1;
        const int rbase = lane >> 1;
#pragma unroll
        for (int it = 0; it < 2; ++it) {
            int row = it * 32 + rbase;
            short8 v = *(const short8*)(ob + row * 20 + colchunk * 8);
            size_t goff = ((size_t)(b * S_LEN + s0 + sOff + row)) * 256
                        + co0 + cOff + j * 16 + colchunk * 8;
            *(short8*)(out + goff) = v;
        }
    }
#undef DEC_PREFETCH
#undef DEC_WRITEBUF
}

// ---------------------------------------------------------------------------
// Decoder conv3, LDS-tiled (unchanged).
// ---------------------------------------------------------------------------
__global__ __launch_bounds__(256) void dec_conv3_tiled_kernel(
        const short* __restrict__ h, const float* __restrict__ w3t,
        const float* __restrict__ b3, const float* __restrict__ x,
        float* __restrict__ xr, float* __restrict__ acc_recon) {
    __shared__ short Zs[66 * 264];
    __shared__ float ws[3 * 256];
    __shared__ float wsum[4];
    int tid = threadIdx.x;
    int b = blockIdx.y;
    int s0 = blockIdx.x * 64;
    const short* hb = h + (size_t)b * S_LEN * HCH;
    for (int i = tid; i < 768; i += 256) ws[i] = w3t[i];
    for (int c = tid; c < 2112; c += 256) {
        int r = c >> 5, part = c & 31;
        int g = s0 - 1 + r;
        short8 v = {0, 0, 0, 0, 0, 0, 0, 0};
        if (g >= 0 && g < S_LEN)
            v = *(const short8*)(hb + (size_t)g * HCH + part * 8);
        *(short8*)(Zs + r * 264 + part * 8) = v;
    }
    __syncthreads();

    int quarter = tid & 3;
    int sl = tid >> 2;
    float a0 = 0.f, a1 = 0.f, a2 = 0.f, a3 = 0.f;
#pragma unroll
    for (int t = 0; t < 3; ++t) {
        const short* zrow = Zs + (sl + t) * 264 + quarter * 64;
        const float* wrow = ws + t * 256 + quarter * 64;
#pragma unroll
        for (int c = 0; c < 8; ++c) {
            bf16x8 v = *(const bf16x8*)(zrow + c * 8);
            float4 w0 = *(const float4*)(wrow + c * 8);
            float4 w1 = *(const float4*)(wrow + c * 8 + 4);
            a0 = fmaf(w0.x, bf2f((unsigned short)v[0]), a0);
            a1 = fmaf(w0.y, bf2f((unsigned short)v[1]), a1);
            a2 = fmaf(w0.z, bf2f((unsigned short)v[2]), a2);
            a3 = fmaf(w0.w, bf2f((unsigned short)v[3]), a3);
            a0 = fmaf(w1.x, bf2f((unsigned short)v[4]), a0);
            a1 = fmaf(w1.y, bf2f((unsigned short)v[5]), a1);
            a2 = fmaf(w1.z, bf2f((unsigned short)v[6]), a2);
            a3 = fmaf(w1.w, bf2f((unsigned short)v[7]), a3);
        }
    }
    float acc = (a0 + a1) + (a2 + a3);
    acc += __shfl_xor(acc, 1);
    acc += __shfl_xor(acc, 2);
    float df2 = 0.f;
    if (quarter == 0) {
        int s = s0 + sl;
        float tot = acc + b3[0];
        xr[b * S_LEN + s] = tot;
        float df = x[b * S_LEN + s] - tot;
        df2 = df * df;
    }
    for (int off = 32; off > 0; off >>= 1) df2 += __shfl_down(df2, off);
    int lane = tid & 63, wv = tid >> 6;
    if (lane == 0) wsum[wv] = df2;
    __syncthreads();
    if (tid == 0) atomicAdd(acc_recon, wsum[0] + wsum[1] + wsum[2] + wsum[3]);
}

// ---------------------------------------------------------------------------
__global__ void finalize_kernel(const float* __restrict__ accs, float* __restrict__ out) {
    if (threadIdx.x == 0) {
        float vqm = accs[0] / ((float)BATCH * S_LEN * DCH);
        float rm  = accs[1] / ((float)BATCH * S_LEN);
        float vq_loss = vqm * 0.05f;
        float commit  = vqm * 0.15f;
        float recon   = rm * 1.0f;
        out[0] = recon + vq_loss + commit;
        out[1] = recon;
        out[2] = vq_loss;
        out[3] = commit;
    }
}

// ---------------------------------------------------------------------------
extern "C" void kernel_launch(void* const* d_in, const int* in_sizes, int n_in,
                              void* d_out, int out_size, void* d_ws, size_t ws_size,
                              hipStream_t stream) {
    const float* x    = (const float*)d_in[0];
    const float* cb   = (const float*)d_in[1];
    const float* ew1  = (const float*)d_in[2];
    const float* eb1  = (const float*)d_in[3];
    const float* ew2  = (const float*)d_in[4];
    const float* eb2  = (const float*)d_in[5];
    const float* ew3  = (const float*)d_in[6];
    const float* eb3  = (const float*)d_in[7];
    const float* dw1  = (const float*)d_in[8];
    const float* db1  = (const float*)d_in[9];
    const float* dw2  = (const float*)d_in[10];
    const float* db2  = (const float*)d_in[11];
    const float* dw3  = (const float*)d_in[12];
    const float* db3  = (const float*)d_in[13];

    float* out = (float*)d_out;
    float* xr    = out;
    float* idx_f = out + BATCH * S_LEN;
    float* loss_out = out + 2 * BATCH * S_LEN;

    const size_t NH = (size_t)BATCH * S_LEN * HCH;   // 16,777,216
    const size_t ND = (size_t)BATCH * S_LEN * DCH;   // 8,388,608

    short* sp = (short*)d_ws;
    short* h1_hi = sp;
    short* h1_lo = sp + NH;
    short* z_hi  = sp;            // overlays h1 (dead after conv2)
    short* z_lo  = sp + ND;
    short* h1d_bf = sp;           // overlays z (dead after vq+gather_vqsum)
    short* h2_hi = sp + 2 * NH;
    short* h2_lo = sp + 3 * NH;
    short* zq_bf = sp + 2 * NH;   // overlays h2 (dead after conv3)
    short* h2d_bf = sp + 3 * NH;
    short* sm = sp + 4 * NH;
    short* cb_hi = sm; sm += KCODES * DCH;
    short* cb_lo = sm; sm += KCODES * DCH;
    short* w2_hi = sm; sm += 3 * HCH * HCH;
    short* w2_lo = sm; sm += 3 * HCH * HCH;
    short* w3_hi = sm; sm += 3 * DCH * HCH;
    short* w3_lo = sm; sm += 3 * DCH * HCH;
    short* wbf_d1 = sm; sm += 3 * 256 * DCH;
    short* wbf_d2 = sm; sm += 3 * 256 * HCH;
    float* cnorm = (float*)sm;
    int* idxb = (int*)(cnorm + KCODES);
    float* w3t = (float*)(idxb + BATCH * S_LEN);
    float* accs = w3t + 768;

    hipMemsetAsync(accs, 0, 2 * sizeof(float), stream);

    // prep
    prep_cb_split_kernel<<<2, 256, 0, stream>>>(cb, cb_hi, cb_lo, cnorm);
    prep_w_split_kernel<<<(3 * HCH * HCH + 255) / 256, 256, 0, stream>>>(ew2, w2_hi, w2_lo, HCH, HCH);
    prep_w_split_kernel<<<(3 * DCH * HCH + 255) / 256, 256, 0, stream>>>(ew3, w3_hi, w3_lo, DCH, HCH);
    prep_wdec_kernel<<<(3 * 256 * DCH + 255) / 256, 256, 0, stream>>>(dw1, wbf_d1, DCH);
    prep_wdec_kernel<<<(3 * 256 * HCH + 255) / 256, 256, 0, stream>>>(dw2, wbf_d2, HCH);
    prep_w3t_kernel<<<3, 256, 0, stream>>>(dw3, w3t);

    // encoder (split-bf16 MFMA)
    enc_conv1_cl_kernel<<<dim3(S_LEN / 32, BATCH), 256, 0, stream>>>(x, h1_hi, h1_lo, ew1, eb1);
    conv_mfma_split<<<dim3(S_LEN / 128, HCH / 128, BATCH), 256, 0, stream>>>(
        h1_hi, h1_lo, h2_hi, h2_lo, w2_hi, w2_lo, eb2, HCH, HCH, 1);
    conv_mfma_split<<<dim3(S_LEN / 128, DCH / 128, BATCH), 256, 0, stream>>>(
        h2_hi, h2_lo, z_hi, z_lo, w3_hi, w3_lo, eb3, HCH, DCH, 0);

    // VQ
    vq_mfma_kernel<<<(BATCH * S_LEN) / 64, 256, 0, stream>>>(
        z_hi, z_lo, cb_hi, cb_lo, cnorm, idxb, idx_f);
    gather_vqsum_kernel<<<dim3(S_LEN / 32, BATCH), 256, 0, stream>>>(
        cb, idxb, z_hi, z_lo, zq_bf, accs);

    // decoder (bf16 MFMA)
    conv_mfma_cl<<<dim3(S_LEN / 128, 2, BATCH), 256, 0, stream>>>(
        zq_bf, h1d_bf, wbf_d1, db1, DCH);
    conv_mfma_cl<<<dim3(S_LEN / 128, 2, BATCH), 256, 0, stream>>>(
        h1d_bf, h2d_bf, wbf_d2, db2, HCH);
    dec_conv3_tiled_kernel<<<dim3(S_LEN / 64, BATCH), 256, 0, stream>>>(
        h2d_bf, w3t, db3, x, xr, accs + 1);

    finalize_kernel<<<1, 64, 0, stream>>>(accs, loss_out);
}